// Round 14
// baseline (2556.288 us; speedup 1.0000x reference)
//
#include <hip/hip_runtime.h>
#include <hip/hip_fp16.h>
#include <stdint.h>

// MoE top-2: B=2048, D=1024, O=1024, E=8, H=10240, top-2 routing.
#define BTOK 2048
#define DIM 1024
#define ODIM 1024
#define NEXP 8
#define HID 10240
#define CAP 2048

typedef _Float16 half8 __attribute__((ext_vector_type(8)));
typedef __fp16 fp16x2 __attribute__((ext_vector_type(2)));
typedef float floatx4 __attribute__((ext_vector_type(4)));

// ---- workspace layout (bytes) ----
// Common (both paths):
#define WS_HIDDEN_OFF 0UL
#define WS_COUNTS_OFF 83886080UL
#define WS_TOKENS_OFF 83886144UL
#define WS_PROBS_OFF  83951680UL
#define WS_SMALL      84017216UL
// Big path only (fp16-converted operands):
#define WS_FC1H_OFF   84017216UL
#define WS_FC2H_OFF   251789376UL
#define WS_X2H_OFF    419561536UL
#define WS_BIG        423755840UL

// async global->LDS DMA, 16 B per lane; LDS dest = wave-uniform base + lane*16,
// global source address is PER-LANE (enables pre-swizzled-source trick).
typedef __attribute__((address_space(1))) const unsigned int guint;
typedef __attribute__((address_space(3))) unsigned int luint;
__device__ __forceinline__ void gload16(const void* g, void* l) {
    __builtin_amdgcn_global_load_lds((guint*)g, (luint*)l, 16, 0, 0);
}

__device__ __forceinline__ half8 cvt8(float4 a, float4 b) {
    union { fp16x2 h2[4]; half8 h8; } u;
    u.h2[0] = __builtin_amdgcn_cvt_pkrtz(a.x, a.y);
    u.h2[1] = __builtin_amdgcn_cvt_pkrtz(a.z, a.w);
    u.h2[2] = __builtin_amdgcn_cvt_pkrtz(b.x, b.y);
    u.h2[3] = __builtin_amdgcn_cvt_pkrtz(b.z, b.w);
    return u.h8;
}

__device__ __forceinline__ int expert_off(const int* __restrict__ counts, int e) {
    int off = 0;
#pragma unroll
    for (int i = 0; i < NEXP; i++) {
        int c = counts[i];
        off += (i < e) ? c : 0;
    }
    return off;
}

// ---------------- fp32 -> fp16 convert (grid-stride, 8 elems/thread) ------
__global__ void cvt_f32_f16(const float* __restrict__ s, _Float16* __restrict__ d,
                            long n8) {
    long i = (long)blockIdx.x * blockDim.x + threadIdx.x;
    long stride = (long)gridDim.x * blockDim.x;
    const float4* s4 = (const float4*)s;
    half8* d8 = (half8*)d;
    for (; i < n8; i += stride) d8[i] = cvt8(s4[2 * i], s4[2 * i + 1]);
}

// ---------------- gate ----------------
__global__ void gate_kernel(const float* __restrict__ x1,
                            const float* __restrict__ gate_w,
                            const float* __restrict__ gate_b,
                            int* counts, int* tokens, float* probs) {
    int b = blockIdx.x;
    int lane = threadIdx.x;
    const float* xr = x1 + (size_t)b * DIM;
    float acc[NEXP];
#pragma unroll
    for (int e = 0; e < NEXP; e++) acc[e] = 0.f;
    for (int i = 0; i < DIM / 64; i++) {
        int d = lane + i * 64;
        float xv = xr[d];
#pragma unroll
        for (int e = 0; e < NEXP; e++) acc[e] += xv * gate_w[e * DIM + d];
    }
#pragma unroll
    for (int e = 0; e < NEXP; e++)
        for (int off = 32; off > 0; off >>= 1) acc[e] += __shfl_xor(acc[e], off);
    if (lane == 0) {
        float l[NEXP], m = -1e30f;
#pragma unroll
        for (int e = 0; e < NEXP; e++) { l[e] = acc[e] + gate_b[e]; m = fmaxf(m, l[e]); }
        float p[NEXP], s = 0.f;
#pragma unroll
        for (int e = 0; e < NEXP; e++) { p[e] = expf(l[e] - m); s += p[e]; }
        float inv = 1.f / s;
        int e0 = 0; float v0 = p[0];
#pragma unroll
        for (int e = 1; e < NEXP; e++) if (p[e] > v0) { v0 = p[e]; e0 = e; }
        int e1 = -1; float v1 = -1.f;
#pragma unroll
        for (int e = 0; e < NEXP; e++) if (e != e0 && p[e] > v1) { v1 = p[e]; e1 = e; }
        int pos0 = atomicAdd(&counts[e0], 1);
        tokens[e0 * CAP + pos0] = b; probs[e0 * CAP + pos0] = v0 * inv;
        int pos1 = atomicAdd(&counts[e1], 1);
        tokens[e1 * CAP + pos1] = b; probs[e1 * CAP + pos1] = v1 * inv;
    }
}

// =====================================================================
// FP16 PATH (m97-style): 256x128 tile, 512 thr = 8 waves (4M x 2N),
// 64x64/wave, BK=32. LDS: A 16K + B 8K, dbuf = 48 KB -> 3 blocks/CU.
// Staging via global_load_lds w=16 with pre-swizzled GLOBAL source
// (linear LDS dest; reader XOR q^((row>>1)&3) — same family measured
// 0 bank conflicts in rounds 1-9). One __syncthreads per K-step.
// =====================================================================

// GEMM1: hidden = relu(x2h[tok] . w1h^T + b)
__global__ __launch_bounds__(512, 6) void gemm1_h(
    const _Float16* __restrict__ x2h, const _Float16* __restrict__ w1h,
    const float* __restrict__ fc1_b, const int* __restrict__ counts,
    const int* __restrict__ tokens, _Float16* __restrict__ hidden) {
    int d = blockIdx.x;
    int e = d & 7;          // expert -> XCD
    int rest = d >> 3;      // [0, 640)
    int mt = rest & 7;      // mt fastest: co-scheduled blocks share B panel
    int nt = rest >> 3;     // [0, 80)

    int cnt = counts[e];
    int m0 = mt * 256;
    if (m0 >= cnt) return;
    int n0 = nt * 128;
    int off = expert_off(counts, e);

    __shared__ __align__(16) _Float16 As[2 * 256 * 32];  // 32 KB
    __shared__ __align__(16) _Float16 Bs[2 * 128 * 32];  // 16 KB

    int t = threadIdx.x, lane = t & 63, wave = t >> 6;   // 8 waves
    int waveM = wave >> 1, waveN = wave & 1;             // 4M x 2N
    int fr = lane & 15, q = lane >> 4;
    int l4 = lane >> 2, sl = lane & 3;

    // A: 16 chunks of 1KB (16 rows x 64B); wave w owns chunks 2w, 2w+1.
    const _Float16* agp[2];
#pragma unroll
    for (int c = 0; c < 2; c++) {
        int row = (2 * wave + c) * 16 + l4;              // [0,256)
        int g = sl ^ ((row >> 1) & 3);                   // inverse swizzle on source
        int ar = min(m0 + row, cnt - 1);
        agp[c] = x2h + (size_t)tokens[e * CAP + ar] * DIM + g * 8;
    }
    // B: 8 chunks; wave w owns chunk w (rows 16w..16w+15)
    int brow = wave * 16 + l4;
    int bg = sl ^ ((brow >> 1) & 3);
    const _Float16* bgp = w1h + ((size_t)e * HID + n0 + brow) * DIM + bg * 8;

    floatx4 acc[4][4];
#pragma unroll
    for (int mi = 0; mi < 4; mi++)
#pragma unroll
        for (int ni = 0; ni < 4; ni++) acc[mi][ni] = (floatx4){0.f, 0.f, 0.f, 0.f};

    auto ISSUE = [&](int buf, int kt) {
        int ko = kt * 32;  // halves along K
#pragma unroll
        for (int c = 0; c < 2; c++)
            gload16(agp[c] + ko, (char*)As + buf * 16384 + (2 * wave + c) * 1024);
        gload16(bgp + ko, (char*)Bs + buf * 8192 + wave * 1024);
    };

    const int KT = DIM / 32;  // 32
    ISSUE(0, 0);
    __syncthreads();          // drains vmcnt: buf0 resident
    int cur = 0;
    for (int kt = 0; kt < KT; kt++) {
        if (kt + 1 < KT) ISSUE(cur ^ 1, kt + 1);  // DMA next tile; covers ds_read+MFMA
        half8 af[4], bf[4];
        const _Float16* Ar = As + cur * 8192;
        const _Float16* Br = Bs + cur * 4096;
#pragma unroll
        for (int mi = 0; mi < 4; mi++) {
            int row = waveM * 64 + mi * 16 + fr;
            af[mi] = *(const half8*)(Ar + row * 32 + ((q ^ ((row >> 1) & 3)) * 8));
        }
#pragma unroll
        for (int ni = 0; ni < 4; ni++) {
            int row = waveN * 64 + ni * 16 + fr;
            bf[ni] = *(const half8*)(Br + row * 32 + ((q ^ ((row >> 1) & 3)) * 8));
        }
#pragma unroll
        for (int mi = 0; mi < 4; mi++)
#pragma unroll
            for (int ni = 0; ni < 4; ni++)
                acc[mi][ni] = __builtin_amdgcn_mfma_f32_16x16x32_f16(
                    af[mi], bf[ni], acc[mi][ni], 0, 0, 0);
        __syncthreads();      // next buf resident; LDS reads complete
        cur ^= 1;
    }
#pragma unroll
    for (int ni = 0; ni < 4; ni++) {
        int col = n0 + waveN * 64 + ni * 16 + fr;
        float bias = fc1_b[e * HID + col];
#pragma unroll
        for (int mi = 0; mi < 4; mi++) {
#pragma unroll
            for (int r = 0; r < 4; r++) {
                int rl = m0 + waveM * 64 + mi * 16 + q * 4 + r;
                if (rl < cnt) {
                    float v = fmaxf(acc[mi][ni][r] + bias, 0.f);
                    hidden[(size_t)(off + rl) * HID + col] = (_Float16)v;
                }
            }
        }
    }
}

// GEMM2 (split-K x8): out += prob * (hidden . w2h^T + b)
__global__ __launch_bounds__(512, 6) void gemm2_h(
    const _Float16* __restrict__ hidden, const _Float16* __restrict__ w2h,
    const float* __restrict__ fc2_b, const int* __restrict__ counts,
    const int* __restrict__ tokens, const float* __restrict__ probs,
    float* __restrict__ out) {
    int d = blockIdx.x;
    int e = d & 7;
    int rest = d >> 3;          // [0, 512)
    int mt = rest & 7;
    int nt = (rest >> 3) & 7;   // ODIM/128 = 8
    int ks = rest >> 6;         // [0, 8)

    int cnt = counts[e];
    int m0 = mt * 256;
    if (m0 >= cnt) return;
    int n0 = nt * 128;
    int off = expert_off(counts, e);
    int k0 = ks * (HID / 8);    // 1280

    __shared__ __align__(16) _Float16 As[2 * 256 * 32];
    __shared__ __align__(16) _Float16 Bs[2 * 128 * 32];

    int t = threadIdx.x, lane = t & 63, wave = t >> 6;
    int waveM = wave >> 1, waveN = wave & 1;
    int fr = lane & 15, q = lane >> 4;
    int l4 = lane >> 2, sl = lane & 3;

    const _Float16* agp[2];
#pragma unroll
    for (int c = 0; c < 2; c++) {
        int row = (2 * wave + c) * 16 + l4;
        int g = sl ^ ((row >> 1) & 3);
        int ar = min(m0 + row, cnt - 1);
        agp[c] = hidden + (size_t)(off + ar) * HID + k0 + g * 8;
    }
    int brow = wave * 16 + l4;
    int bg = sl ^ ((brow >> 1) & 3);
    const _Float16* bgp = w2h + ((size_t)e * ODIM + n0 + brow) * HID + k0 + bg * 8;

    floatx4 acc[4][4];
#pragma unroll
    for (int mi = 0; mi < 4; mi++)
#pragma unroll
        for (int ni = 0; ni < 4; ni++) acc[mi][ni] = (floatx4){0.f, 0.f, 0.f, 0.f};

    auto ISSUE = [&](int buf, int kt) {
        int ko = kt * 32;
#pragma unroll
        for (int c = 0; c < 2; c++)
            gload16(agp[c] + ko, (char*)As + buf * 16384 + (2 * wave + c) * 1024);
        gload16(bgp + ko, (char*)Bs + buf * 8192 + wave * 1024);
    };

    const int KT = (HID / 8) / 32;  // 40
    ISSUE(0, 0);
    __syncthreads();
    int cur = 0;
    for (int kt = 0; kt < KT; kt++) {
        if (kt + 1 < KT) ISSUE(cur ^ 1, kt + 1);
        half8 af[4], bf[4];
        const _Float16* Ar = As + cur * 8192;
        const _Float16* Br = Bs + cur * 4096;
#pragma unroll
        for (int mi = 0; mi < 4; mi++) {
            int row = waveM * 64 + mi * 16 + fr;
            af[mi] = *(const half8*)(Ar + row * 32 + ((q ^ ((row >> 1) & 3)) * 8));
        }
#pragma unroll
        for (int ni = 0; ni < 4; ni++) {
            int row = waveN * 64 + ni * 16 + fr;
            bf[ni] = *(const half8*)(Br + row * 32 + ((q ^ ((row >> 1) & 3)) * 8));
        }
#pragma unroll
        for (int mi = 0; mi < 4; mi++)
#pragma unroll
            for (int ni = 0; ni < 4; ni++)
                acc[mi][ni] = __builtin_amdgcn_mfma_f32_16x16x32_f16(
                    af[mi], bf[ni], acc[mi][ni], 0, 0, 0);
        __syncthreads();
        cur ^= 1;
    }
#pragma unroll
    for (int ni = 0; ni < 4; ni++) {
        int col = n0 + waveN * 64 + ni * 16 + fr;
        float bias = (ks == 0) ? fc2_b[e * ODIM + col] : 0.f;
#pragma unroll
        for (int mi = 0; mi < 4; mi++) {
#pragma unroll
            for (int r = 0; r < 4; r++) {
                int rl = m0 + waveM * 64 + mi * 16 + q * 4 + r;
                if (rl < cnt) {
                    float p = probs[e * CAP + rl];
                    int tok = tokens[e * CAP + rl];
                    atomicAdd(&out[(size_t)tok * ODIM + col],
                              p * (acc[mi][ni][r] + bias));
                }
            }
        }
    }
}

// =====================================================================
// FALLBACK PATH — round-1 verbatim (best measured: 1160 us total).
// 256x256 tile, 1024 thr, reg-staged fp32->fp16, __syncthreads dbuf.
// =====================================================================
#define BMf 256
#define BNf 256
#define BKf 32
#define KSPLf 8

__global__ __launch_bounds__(1024, 4) void gemm1_f(
    const float* __restrict__ x2, const float* __restrict__ fc1_w,
    const float* __restrict__ fc1_b, const int* __restrict__ counts,
    const int* __restrict__ tokens, _Float16* __restrict__ hidden) {
    int d = blockIdx.x;
    int e = d & 7;
    int rest = d >> 3;
    int nt = rest >> 3;
    int mt = rest & 7;

    int cnt = counts[e];
    int m0 = mt * BMf;
    if (m0 >= cnt) return;
    int n0 = nt * BNf;
    int off = expert_off(counts, e);

    __shared__ __align__(16) _Float16 As[2 * BMf * BKf];
    __shared__ __align__(16) _Float16 Bs[2 * BNf * BKf];

    int t = threadIdx.x;
    int lane = t & 63, wave = t >> 6;
    int waveM = wave >> 2, waveN = wave & 3;
    int fr = lane & 15, q = lane >> 4;

    int srow = t >> 2;
    int sg = t & 3;
    int swz = sg ^ ((srow >> 1) & 3);
    int arow = min(m0 + srow, cnt - 1);
    const float* ag = x2 + (size_t)tokens[e * CAP + arow] * DIM + sg * 8;
    const float* bg = fc1_w + ((size_t)e * HID + n0 + srow) * DIM + sg * 8;
    _Float16* aw = As + srow * BKf + swz * 8;
    _Float16* bw = Bs + srow * BKf + swz * 8;

    floatx4 acc[4][4];
#pragma unroll
    for (int mi = 0; mi < 4; mi++)
#pragma unroll
        for (int ni = 0; ni < 4; ni++) acc[mi][ni] = (floatx4){0.f, 0.f, 0.f, 0.f};

    float4 pa0, pa1, pb0, pb1;
    auto LOADT = [&](int kt) {
        const float* a_ = ag + kt * BKf;
        const float* b_ = bg + kt * BKf;
        pa0 = *(const float4*)a_;
        pa1 = *(const float4*)(a_ + 4);
        pb0 = *(const float4*)b_;
        pb1 = *(const float4*)(b_ + 4);
    };
    auto WRITET = [&](int buf) {
        *(half8*)(aw + buf * (BMf * BKf)) = cvt8(pa0, pa1);
        *(half8*)(bw + buf * (BNf * BKf)) = cvt8(pb0, pb1);
    };

    const int KT = DIM / BKf;
    LOADT(0);
    WRITET(0);
    LOADT(1);
    __syncthreads();
    int cur = 0;
    for (int kt = 0; kt < KT; kt++) {
        half8 af[4], bf[4];
        const _Float16* Ar = As + cur * (BMf * BKf);
        const _Float16* Br = Bs + cur * (BNf * BKf);
#pragma unroll
        for (int mi = 0; mi < 4; mi++) {
            int row = waveM * 64 + mi * 16 + fr;
            af[mi] = *(const half8*)(Ar + row * BKf + ((q ^ ((row >> 1) & 3)) * 8));
        }
#pragma unroll
        for (int ni = 0; ni < 4; ni++) {
            int row = waveN * 64 + ni * 16 + fr;
            bf[ni] = *(const half8*)(Br + row * BKf + ((q ^ ((row >> 1) & 3)) * 8));
        }
        __syncthreads();
        if (kt + 1 < KT) WRITET(cur ^ 1);
        if (kt + 2 < KT) LOADT(kt + 2);
#pragma unroll
        for (int mi = 0; mi < 4; mi++)
#pragma unroll
            for (int ni = 0; ni < 4; ni++)
                acc[mi][ni] = __builtin_amdgcn_mfma_f32_16x16x32_f16(
                    af[mi], bf[ni], acc[mi][ni], 0, 0, 0);
        __syncthreads();
        cur ^= 1;
    }
#pragma unroll
    for (int ni = 0; ni < 4; ni++) {
        int col = n0 + waveN * 64 + ni * 16 + fr;
        float bias = fc1_b[e * HID + col];
#pragma unroll
        for (int mi = 0; mi < 4; mi++) {
#pragma unroll
            for (int r = 0; r < 4; r++) {
                int rl = m0 + waveM * 64 + mi * 16 + q * 4 + r;
                if (rl < cnt) {
                    float v = fmaxf(acc[mi][ni][r] + bias, 0.f);
                    hidden[(size_t)(off + rl) * HID + col] = (_Float16)v;
                }
            }
        }
    }
}

__global__ __launch_bounds__(1024, 4) void gemm2_f(
    const _Float16* __restrict__ hidden, const float* __restrict__ fc2_w,
    const float* __restrict__ fc2_b, const int* __restrict__ counts,
    const int* __restrict__ tokens, const float* __restrict__ probs,
    float* __restrict__ out) {
    int d = blockIdx.x;
    int e = d & 7;
    int rest = d >> 3;
    int mt = rest & 7;
    int nt = (rest >> 3) & 3;
    int ks = rest >> 5;

    int cnt = counts[e];
    int m0 = mt * BMf;
    if (m0 >= cnt) return;
    int n0 = nt * BNf;
    int off = expert_off(counts, e);
    int k0 = ks * (HID / KSPLf);

    __shared__ __align__(16) _Float16 As[2 * BMf * BKf];
    __shared__ __align__(16) _Float16 Bs[2 * BNf * BKf];

    int t = threadIdx.x;
    int lane = t & 63, wave = t >> 6;
    int waveM = wave >> 2, waveN = wave & 3;
    int fr = lane & 15, q = lane >> 4;

    int srow = t >> 2;
    int sg = t & 3;
    int swz = sg ^ ((srow >> 1) & 3);
    int arow = min(m0 + srow, cnt - 1);
    const _Float16* ag = hidden + (size_t)(off + arow) * HID + k0 + sg * 8;
    const float* bg = fc2_w + ((size_t)e * ODIM + n0 + srow) * HID + k0 + sg * 8;
    _Float16* aw = As + srow * BKf + swz * 8;
    _Float16* bw = Bs + srow * BKf + swz * 8;

    floatx4 acc[4][4];
#pragma unroll
    for (int mi = 0; mi < 4; mi++)
#pragma unroll
        for (int ni = 0; ni < 4; ni++) acc[mi][ni] = (floatx4){0.f, 0.f, 0.f, 0.f};

    half8 pa;
    float4 pb0, pb1;
    auto LOADT = [&](int kt) {
        pa = *(const half8*)(ag + kt * BKf);
        const float* b_ = bg + kt * BKf;
        pb0 = *(const float4*)b_;
        pb1 = *(const float4*)(b_ + 4);
    };
    auto WRITET = [&](int buf) {
        *(half8*)(aw + buf * (BMf * BKf)) = pa;
        *(half8*)(bw + buf * (BNf * BKf)) = cvt8(pb0, pb1);
    };

    const int KT = (HID / KSPLf) / BKf;
    LOADT(0);
    WRITET(0);
    LOADT(1);
    __syncthreads();
    int cur = 0;
    for (int kt = 0; kt < KT; kt++) {
        half8 af[4], bf[4];
        const _Float16* Ar = As + cur * (BMf * BKf);
        const _Float16* Br = Bs + cur * (BNf * BKf);
#pragma unroll
        for (int mi = 0; mi < 4; mi++) {
            int row = waveM * 64 + mi * 16 + fr;
            af[mi] = *(const half8*)(Ar + row * BKf + ((q ^ ((row >> 1) & 3)) * 8));
        }
#pragma unroll
        for (int ni = 0; ni < 4; ni++) {
            int row = waveN * 64 + ni * 16 + fr;
            bf[ni] = *(const half8*)(Br + row * BKf + ((q ^ ((row >> 1) & 3)) * 8));
        }
        __syncthreads();
        if (kt + 1 < KT) WRITET(cur ^ 1);
        if (kt + 2 < KT) LOADT(kt + 2);
#pragma unroll
        for (int mi = 0; mi < 4; mi++)
#pragma unroll
            for (int ni = 0; ni < 4; ni++)
                acc[mi][ni] = __builtin_amdgcn_mfma_f32_16x16x32_f16(
                    af[mi], bf[ni], acc[mi][ni], 0, 0, 0);
        __syncthreads();
        cur ^= 1;
    }
#pragma unroll
    for (int ni = 0; ni < 4; ni++) {
        int col = n0 + waveN * 64 + ni * 16 + fr;
        float bias = (ks == 0) ? fc2_b[e * ODIM + col] : 0.f;
#pragma unroll
        for (int mi = 0; mi < 4; mi++) {
#pragma unroll
            for (int r = 0; r < 4; r++) {
                int rl = m0 + waveM * 64 + mi * 16 + q * 4 + r;
                if (rl < cnt) {
                    float p = probs[e * CAP + rl];
                    int tok = tokens[e * CAP + rl];
                    atomicAdd(&out[(size_t)tok * ODIM + col],
                              p * (acc[mi][ni][r] + bias));
                }
            }
        }
    }
}

extern "C" void kernel_launch(void* const* d_in, const int* in_sizes, int n_in,
                              void* d_out, int out_size, void* d_ws, size_t ws_size,
                              hipStream_t stream) {
    if (ws_size < WS_SMALL) return;
    const float* x1 = (const float*)d_in[0];
    const float* x2 = (const float*)d_in[1];
    const float* gate_w = (const float*)d_in[2];
    const float* gate_b = (const float*)d_in[3];
    const float* fc1_w = (const float*)d_in[4];
    const float* fc1_b = (const float*)d_in[5];
    const float* fc2_w = (const float*)d_in[6];
    const float* fc2_b = (const float*)d_in[7];
    float* out = (float*)d_out;
    char* ws = (char*)d_ws;
    _Float16* hidden = (_Float16*)(ws + WS_HIDDEN_OFF);
    int* counts = (int*)(ws + WS_COUNTS_OFF);
    int* tokens = (int*)(ws + WS_TOKENS_OFF);
    float* probs = (float*)(ws + WS_PROBS_OFF);

    (void)hipMemsetAsync(counts, 0, 2 * NEXP * sizeof(int), stream);
    (void)hipMemsetAsync(d_out, 0, (size_t)out_size * sizeof(float), stream);
    gate_kernel<<<BTOK, 64, 0, stream>>>(x1, gate_w, gate_b, counts, tokens, probs);

    if (ws_size >= WS_BIG) {
        _Float16* fc1h = (_Float16*)(ws + WS_FC1H_OFF);
        _Float16* fc2h = (_Float16*)(ws + WS_FC2H_OFF);
        _Float16* x2h = (_Float16*)(ws + WS_X2H_OFF);
        cvt_f32_f16<<<2048, 256, 0, stream>>>(fc1_w, fc1h, 10485760L);
        cvt_f32_f16<<<2048, 256, 0, stream>>>(fc2_w, fc2h, 10485760L);
        cvt_f32_f16<<<512, 256, 0, stream>>>(x2, x2h, 262144L);
        gemm1_h<<<8 * 80 * 8, 512, 0, stream>>>(x2h, fc1h, fc1_b, counts, tokens,
                                                hidden);
        gemm2_h<<<8 * 8 * 8 * 8, 512, 0, stream>>>(hidden, fc2h, fc2_b, counts,
                                                   tokens, probs, out);
    } else {
        gemm1_f<<<(CAP / BMf) * (HID / BNf) * NEXP, 1024, 0, stream>>>(
            x2, fc1_w, fc1_b, counts, tokens, hidden);
        gemm2_f<<<(CAP / BMf) * (ODIM / BNf) * NEXP * KSPLf, 1024, 0, stream>>>(
            hidden, fc2_w, fc2_b, counts, tokens, probs, out);
    }
}